// Round 5
// baseline (158.983 us; speedup 1.0000x reference)
//
#include <hip/hip_runtime.h>
#include <stdint.h>

#define HH 512
#define WW 512
#define NIMG 64
#define OH 510
#define OW 510
#define NB 512
#define NTILE 9        // column tiles: 62 output cols each (64 loaded, 2 halo)
#define NSEG 8         // row segments: 64 output rows (last = 62)
#define NREP 64        // replicated global histograms (contention /64)
#define BLOCK 256
#define NTASK (NIMG * 2 * NTILE * NSEG)   // 9216
#define NBLK (NTASK / 4)                  // 2304 blocks, 4 waves each

// Replicate reference binarization bit-exactly in float32:
// b = ((x*0.5 + 0.5) * 255.0) > 127.5
__device__ __forceinline__ int predbit(float x) {
    return ((x * 0.5f + 0.5f) * 255.0f > 127.5f) ? 1 : 0;
}

__global__ __launch_bounds__(BLOCK) void hist_kernel(const float* __restrict__ inp,
                                                     const float* __restrict__ tgt,
                                                     int* __restrict__ rep) {
    __shared__ int hist[NB];
    const int tid  = threadIdx.x;
    const int lane = tid & 63;
    const int wave = tid >> 6;

    for (int i = tid; i < NB; i += BLOCK) hist[i] = 0;
    __syncthreads();

    // task decode: seg fastest (4 consecutive segs -> the 4 waves of a block)
    const int task = blockIdx.x * 4 + wave;
    const int seg  = task & (NSEG - 1);
    const int rst  = task >> 3;
    const int tile = rst % NTILE;
    const int rst2 = rst / NTILE;
    const int t    = rst2 & 1;
    const int img  = rst2 >> 1;

    const int r0 = seg * 64;                    // first output row
    const int R  = min(64, OH - r0);            // 64, last seg 62
    const int colbase = tile * 62;
    const int col   = min(colbase + lane, WW - 1);   // clamp tile-8 halo lanes
    const bool valid = (lane < 62) && (colbase + lane < OW);
    const int sign = 1 - 2 * t;

    const float* p = (t ? tgt : inp) + (size_t)img * HH * WW + (size_t)r0 * WW + col;
    // p[r * WW] = this lane's column, input row r0+r

    // ---- pipeline preamble: masks for rows 0,1; preload rows 2..5 ----
    unsigned long long m0 = __ballot(predbit(p[0]));
    unsigned long long m1 = __ballot(predbit(p[WW]));
    float x0 = p[2 * WW], x1 = p[3 * WW], x2 = p[4 * WW], x3 = p[5 * WW];

    // ---- main loop: no barriers, loads stay 4 deep in flight ----
    int o = 0;
    for (; o + 4 <= R; o += 4) {
        {   unsigned long long m2 = __ballot(predbit(x0));
            int code = (int)((m0 >> lane) & 7) | ((int)((m1 >> lane) & 7) << 3)
                     | ((int)((m2 >> lane) & 7) << 6);
            if (valid) atomicAdd(&hist[code], sign);
            m0 = m1; m1 = m2;
            int rl = o + 6; if (rl > R + 1) rl = R + 1;
            x0 = p[rl * WW]; }
        {   unsigned long long m2 = __ballot(predbit(x1));
            int code = (int)((m0 >> lane) & 7) | ((int)((m1 >> lane) & 7) << 3)
                     | ((int)((m2 >> lane) & 7) << 6);
            if (valid) atomicAdd(&hist[code], sign);
            m0 = m1; m1 = m2;
            int rl = o + 7; if (rl > R + 1) rl = R + 1;
            x1 = p[rl * WW]; }
        {   unsigned long long m2 = __ballot(predbit(x2));
            int code = (int)((m0 >> lane) & 7) | ((int)((m1 >> lane) & 7) << 3)
                     | ((int)((m2 >> lane) & 7) << 6);
            if (valid) atomicAdd(&hist[code], sign);
            m0 = m1; m1 = m2;
            int rl = o + 8; if (rl > R + 1) rl = R + 1;
            x2 = p[rl * WW]; }
        {   unsigned long long m2 = __ballot(predbit(x3));
            int code = (int)((m0 >> lane) & 7) | ((int)((m1 >> lane) & 7) << 3)
                     | ((int)((m2 >> lane) & 7) << 6);
            if (valid) atomicAdd(&hist[code], sign);
            m0 = m1; m1 = m2;
            int rl = o + 9; if (rl > R + 1) rl = R + 1;
            x3 = p[rl * WW]; }
    }
    // remainder (last seg only, <=3 iters): direct loads
    for (; o < R; ++o) {
        unsigned long long m2 = __ballot(predbit(p[(o + 2) * WW]));
        int code = (int)((m0 >> lane) & 7) | ((int)((m1 >> lane) & 7) << 3)
                 | ((int)((m2 >> lane) & 7) << 6);
        if (valid) atomicAdd(&hist[code], sign);
        m0 = m1; m1 = m2;
    }

    __syncthreads();
    // flush to one of NREP replicated global histograms (contention /NREP)
    const int rid = blockIdx.x & (NREP - 1);
    for (int i = tid; i < NB; i += BLOCK) {
        int v = hist[i];
        if (v) atomicAdd(&rep[rid * NB + i], v);
    }
}

__global__ __launch_bounds__(NB) void reduce_kernel(const int* __restrict__ rep,
                                                    float* __restrict__ out) {
    __shared__ double sdata[NB];
    int tid = threadIdx.x;
    int s = 0;
    #pragma unroll
    for (int r = 0; r < NREP; ++r) s += rep[r * NB + tid];   // coalesced across tid
    double d = (double)s;
    sdata[tid] = d * d;
    __syncthreads();
    for (int stp = NB / 2; stp > 0; stp >>= 1) {
        if (tid < stp) sdata[tid] += sdata[tid + stp];
        __syncthreads();
    }
    if (tid == 0) {
        const double n = (double)NIMG * OH * OW;   // 16,646,400
        out[0] = (float)(sdata[0] / (n * n) / 512.0 / 64.0);
    }
}

extern "C" void kernel_launch(void* const* d_in, const int* in_sizes, int n_in,
                              void* d_out, int out_size, void* d_ws, size_t ws_size,
                              hipStream_t stream) {
    const float* inp = (const float*)d_in[0];
    const float* tgt = (const float*)d_in[1];
    float* out = (float*)d_out;
    int* rep = (int*)d_ws;                      // NREP*NB ints = 128 KB in workspace

    hipMemsetAsync(rep, 0, NREP * NB * sizeof(int), stream);
    hist_kernel<<<NBLK, BLOCK, 0, stream>>>(inp, tgt, rep);
    reduce_kernel<<<1, NB, 0, stream>>>(rep, out);
}

// Round 8
// 151.223 us; speedup vs baseline: 1.0513x; 1.0513x over previous
//
#include <hip/hip_runtime.h>
#include <stdint.h>

#define HH 512
#define WW 512
#define NIMG 64
#define OH 510
#define OW 510
#define NB 512
#define SEGR 16                      // output rows per big segment
#define NSEG 32
#define NREP 64
#define BLOCK 256
#define NBIG (NIMG * 2 * NSEG * 2)   // 8192 big wave-tasks (2 col-tiles)
#define NSEAM (NIMG * 2 * 8)         // 1024 seam wave-tasks (cols 254,255)
#define NBLK ((NBIG + NSEAM) / 4)    // 2304 blocks, 4 waves each
#define HBINS 576                    // 512 real + 64 per-lane dummy bins

typedef float f4 __attribute__((ext_vector_type(4)));

// Pinned load, flat VGPR-address form. volatile => program order kept among asm.
__device__ __forceinline__ f4 ldg4(const float* addr) {
    f4 r;
    asm volatile("global_load_dwordx4 %0, %1, off" : "=v"(r) : "v"(addr));
    return r;
}
// Wait until <=N of MY loads outstanding; "+v" tie orders consumption of x after it.
template<int N>
__device__ __forceinline__ void waitv(f4& x) {
    if      constexpr (N == 7) asm volatile("s_waitcnt vmcnt(7)" : "+v"(x));
    else if constexpr (N == 6) asm volatile("s_waitcnt vmcnt(6)" : "+v"(x));
    else if constexpr (N == 5) asm volatile("s_waitcnt vmcnt(5)" : "+v"(x));
    else if constexpr (N == 4) asm volatile("s_waitcnt vmcnt(4)" : "+v"(x));
    else if constexpr (N == 3) asm volatile("s_waitcnt vmcnt(3)" : "+v"(x));
    else if constexpr (N == 2) asm volatile("s_waitcnt vmcnt(2)" : "+v"(x));
    else if constexpr (N == 1) asm volatile("s_waitcnt vmcnt(1)" : "+v"(x));
    else                       asm volatile("s_waitcnt vmcnt(0)" : "+v"(x));
}

// Reference binarization ((x*0.5+0.5)*255 > 127.5) is exactly (x > 2^-24) in f32:
// x*0.5 is exact; 0.5 + x*0.5 rounds above 0.5 iff x*0.5 > 2^-25 (tie-to-even at
// exactly 2^-25); *255 preserves strict ordering around 127.5.
#define BINC 0x1p-24f

__device__ __forceinline__ int pack4(f4 v) {
    return (v.x > BINC) | ((v.y > BINC) << 1) | ((v.z > BINC) << 2) | ((v.w > BINC) << 3);
}

__global__ __launch_bounds__(BLOCK) void hist_kernel(const float* __restrict__ inp,
                                                     const float* __restrict__ tgt,
                                                     int* __restrict__ rep) {
    __shared__ int hist[HBINS];
    const int tid  = threadIdx.x;
    const int lane = tid & 63;
    const int wave = tid >> 6;

    for (int i = tid; i < HBINS; i += BLOCK) hist[i] = 0;
    __syncthreads();

    const int task  = blockIdx.x * 4 + wave;
    const int dummy = 512 + lane;      // per-lane dummy bin (uniform flow, no branch)

    if (task < NBIG) {
        // ---- big task: tile fastest, then seg, t, img ----
        const int tile = task & 1;
        const int seg  = (task >> 1) & 31;
        const int t    = (task >> 6) & 1;
        const int img  = task >> 7;
        const int r0   = seg * SEGR;
        const int R    = min(SEGR, OH - r0);        // 16 (seg 31: 14)
        const int c0   = tile * 256 + 4 * lane;     // lane's first col (16B aligned)
        const int sign = 1 - 2 * t;
        const float* base = (t ? tgt : inp) + (size_t)img * (HH * WW) + c0;
        auto ap = [&](int rel) { return base + (size_t)min(r0 + rel, HH - 1) * WW; };

        // ring of 8, every load consumed by a matching wait (no dead dests)
        f4 X[8];
        #pragma unroll
        for (int k = 0; k < 8; ++k) X[k] = ldg4(ap(k));

        int n0, n1, n2;
        waitv<7>(X[0]);
        { int nib = pack4(X[0]); n0 = nib | (__shfl_down(nib, 1) << 4); }
        X[0] = ldg4(ap(8));
        waitv<7>(X[1]);
        { int nib = pack4(X[1]); n1 = nib | (__shfl_down(nib, 1) << 4); }
        X[1] = ldg4(ap(9));

        // issued rows 0..9; refills rows 10..17 at o=0..7; drain o=9..15
        #define STEP(o, W) { \
            f4& Xs = X[((o) + 2) & 7]; \
            waitv<W>(Xs); \
            int nib = pack4(Xs); \
            n2 = nib | (__shfl_down(nib, 1) << 4); \
            if ((o) <= 7) Xs = ldg4(ap((o) + 10)); \
            if ((o) < R) { \
                _Pragma("unroll") \
                for (int j = 0; j < 4; ++j) { \
                    int code = ((n0 >> j) & 7) | (((n1 >> j) & 7) << 3) \
                             | (((n2 >> j) & 7) << 6); \
                    int slot = (lane < 63 || j < 2) ? code : dummy; \
                    atomicAdd(&hist[slot], sign); \
                } \
            } \
            n0 = n1; n1 = n2; }

        STEP(0, 7)  STEP(1, 7)  STEP(2, 7)  STEP(3, 7)
        STEP(4, 7)  STEP(5, 7)  STEP(6, 7)  STEP(7, 7)
        STEP(8, 7)  STEP(9, 6)  STEP(10, 5) STEP(11, 4)
        STEP(12, 3) STEP(13, 2) STEP(14, 1) STEP(15, 0)
        #undef STEP
        // vmcnt == 0 here: all loads consumed, nothing in flight.
    } else {
        // ---- seam task: outputs cols 254,255 (inputs 254..257), 64 rows ----
        const int idx = task - NBIG;
        const int seg = idx & 7;
        const int t   = (idx >> 3) & 1;
        const int img = idx >> 4;
        const int sign = 1 - 2 * t;
        const int r   = seg * 64 + lane;
        const bool v  = (r < OH);
        const float* bp = (t ? tgt : inp) + (size_t)img * (HH * WW);
        int p[3];
        #pragma unroll
        for (int k = 0; k < 3; ++k) {
            const float* rowp = bp + (size_t)min(r + k, HH - 1) * WW;
            float2 A = *(const float2*)(rowp + 254);   // cols 254,255 (8B aligned)
            float2 B = *(const float2*)(rowp + 256);   // cols 256,257
            p[k] = (A.x > BINC) | ((A.y > BINC) << 1)
                 | ((B.x > BINC) << 2) | ((B.y > BINC) << 3);
        }
        int c254 = (p[0] & 7) | ((p[1] & 7) << 3) | ((p[2] & 7) << 6);
        int c255 = ((p[0] >> 1) & 7) | (((p[1] >> 1) & 7) << 3) | (((p[2] >> 1) & 7) << 6);
        atomicAdd(&hist[v ? c254 : dummy], sign);
        atomicAdd(&hist[v ? c255 : dummy], sign);
    }

    __syncthreads();
    const int rid = blockIdx.x & (NREP - 1);
    for (int i = tid; i < NB; i += BLOCK) {            // flush real bins only
        int vv = hist[i];
        if (vv) atomicAdd(&rep[rid * NB + i], vv);
    }
}

__global__ __launch_bounds__(NB) void reduce_kernel(const int* __restrict__ rep,
                                                    float* __restrict__ out) {
    __shared__ double sdata[NB];
    int tid = threadIdx.x;
    int s = 0;
    #pragma unroll
    for (int r = 0; r < NREP; ++r) s += rep[r * NB + tid];   // coalesced across tid
    double d = (double)s;
    sdata[tid] = d * d;
    __syncthreads();
    for (int stp = NB / 2; stp > 0; stp >>= 1) {
        if (tid < stp) sdata[tid] += sdata[tid + stp];
        __syncthreads();
    }
    if (tid == 0) {
        const double n = (double)NIMG * OH * OW;   // 16,646,400
        out[0] = (float)(sdata[0] / (n * n) / 512.0 / 64.0);
    }
}

extern "C" void kernel_launch(void* const* d_in, const int* in_sizes, int n_in,
                              void* d_out, int out_size, void* d_ws, size_t ws_size,
                              hipStream_t stream) {
    const float* inp = (const float*)d_in[0];
    const float* tgt = (const float*)d_in[1];
    float* out = (float*)d_out;
    int* rep = (int*)d_ws;                      // NREP*NB ints = 128 KB in workspace

    hipMemsetAsync(rep, 0, NREP * NB * sizeof(int), stream);
    hist_kernel<<<NBLK, BLOCK, 0, stream>>>(inp, tgt, rep);
    reduce_kernel<<<1, NB, 0, stream>>>(rep, out);
}